// Round 3
// baseline (31513.989 us; speedup 1.0000x reference)
//
#include <hip/hip_runtime.h>
#include <stdint.h>

// Problem dims (fixed by the reference)
#define BSZ   1024
#define TT    8
#define DD    512
#define HH    512
#define NSEQ  (BSZ*TT)          // 8192 sequential steps per direction
#define FOURH (4*HH)            // 2048
#define POISON 0xAAAAAAAAu
#define G_ELEMS  ((size_t)2*NSEQ*FOURH)      // 33,554,432 floats (128 MB)
#define HB_ELEMS ((size_t)2*(NSEQ+1)*HH)     //  8,389,632 floats (32 MB)

typedef __attribute__((ext_vector_type(4))) float vf4;

// IC-coherent 16B load (bypasses L1+L2; no cache-invalidate side effects).
__device__ __forceinline__ vf4 ld16_ic(const float* p){
  vf4 r;
  asm volatile("global_load_dwordx4 %0, %1, off sc0 sc1\n\t"
               "s_waitcnt vmcnt(0)"
               : "=v"(r) : "v"(p) : "memory");
  return r;
}
// IC-coherent 4B publish store.
__device__ __forceinline__ void st_ic(float* p, float v){
  asm volatile("global_store_dword %0, %1, off sc0 sc1"
               :: "v"(p), "v"(v) : "memory");
}

// ---------------------------------------------------------------------------
// Init: poison the h-pipeline buffer, seed slot 0 with h0 (LSB-flip if it
// happens to equal the poison bit pattern).
// ---------------------------------------------------------------------------
__global__ void init_hbuf_k(float* __restrict__ hbuf, const float* __restrict__ h0)
{
  size_t idx = (size_t)blockIdx.x*blockDim.x + threadIdx.x;
  if (idx >= HB_ELEMS) return;
  int j = (int)(idx % HH);
  size_t r = idx / HH;
  int t   = (int)(r % (NSEQ+1));
  int dir = (int)(r / (NSEQ+1));
  uint32_t v;
  if (t == 0){
    uint32_t u = __float_as_uint(h0[dir*HH + j]);
    if (u == POISON) u ^= 1u;
    v = u;
  } else {
    v = POISON;
  }
  ((uint32_t*)hbuf)[idx] = v;
}

// ---------------------------------------------------------------------------
// Input-side GEMM: g[dir][n][m] = x[row]·W_ih_dir[m] + b_dir[m]
//   dir 0: row = n ; dir 1: row = n^7  (per-sample time reversal, T=8)
// ---------------------------------------------------------------------------
__global__ __launch_bounds__(256) void gemm_ih_k(
    const float* __restrict__ x,
    const float* __restrict__ Wf, const float* __restrict__ bf,
    const float* __restrict__ Wb, const float* __restrict__ bb,
    float* __restrict__ g)
{
  const int bm = blockIdx.x;          // 128 row tiles
  const int bn = blockIdx.y;          // 64 col tiles over combined N=4096
  const int n0  = bm*64;
  const int m0g = bn*64;
  const int dir = m0g >> 11;          // /2048
  const int m0  = m0g & 2047;
  const float* __restrict__ W    = dir ? Wb : Wf;
  const float* __restrict__ bias = dir ? bb : bf;

  __shared__ float As[32][68];
  __shared__ float Bs[32][68];

  const int tid = threadIdx.x;
  const int tx = tid & 15, ty = tid >> 4;
  float acc[4][4] = {};

  const int lr = tid >> 2;            // 0..63
  const int lk = (tid & 3) * 8;       // 0,8,16,24
  int arow = n0 + lr; if (dir) arow ^= 7;
  const float* ap = &x[(size_t)arow*DD];
  const float* wp = &W[(size_t)(m0+lr)*DD];

  for (int k0 = 0; k0 < DD; k0 += 32){
    float4 a0 = *(const float4*)&ap[k0+lk];
    float4 a1 = *(const float4*)&ap[k0+lk+4];
    float4 w0 = *(const float4*)&wp[k0+lk];
    float4 w1 = *(const float4*)&wp[k0+lk+4];
    __syncthreads();
    As[lk+0][lr]=a0.x; As[lk+1][lr]=a0.y; As[lk+2][lr]=a0.z; As[lk+3][lr]=a0.w;
    As[lk+4][lr]=a1.x; As[lk+5][lr]=a1.y; As[lk+6][lr]=a1.z; As[lk+7][lr]=a1.w;
    Bs[lk+0][lr]=w0.x; Bs[lk+1][lr]=w0.y; Bs[lk+2][lr]=w0.z; Bs[lk+3][lr]=w0.w;
    Bs[lk+4][lr]=w1.x; Bs[lk+5][lr]=w1.y; Bs[lk+6][lr]=w1.z; Bs[lk+7][lr]=w1.w;
    __syncthreads();
    #pragma unroll
    for (int kk = 0; kk < 32; kk++){
      float4 av = *(const float4*)&As[kk][ty*4];
      float4 bv = *(const float4*)&Bs[kk][tx*4];
      acc[0][0]+=av.x*bv.x; acc[0][1]+=av.x*bv.y; acc[0][2]+=av.x*bv.z; acc[0][3]+=av.x*bv.w;
      acc[1][0]+=av.y*bv.x; acc[1][1]+=av.y*bv.y; acc[1][2]+=av.y*bv.z; acc[1][3]+=av.y*bv.w;
      acc[2][0]+=av.z*bv.x; acc[2][1]+=av.z*bv.y; acc[2][2]+=av.z*bv.z; acc[2][3]+=av.z*bv.w;
      acc[3][0]+=av.w*bv.x; acc[3][1]+=av.w*bv.y; acc[3][2]+=av.w*bv.z; acc[3][3]+=av.w*bv.w;
    }
  }

  const size_t gbase = (size_t)dir*NSEQ*FOURH;
  #pragma unroll
  for (int i = 0; i < 4; i++){
    const int n = n0 + ty*4 + i;
    #pragma unroll
    for (int j = 0; j < 4; j++){
      const int m = m0 + tx*4 + j;
      g[gbase + (size_t)n*FOURH + m] = acc[i][j] + bias[m];
    }
  }
}

// ---------------------------------------------------------------------------
// Sequential bidirectional scan — barrier-free, wave-autonomous.
// 64 wgs (32/dir) x 1024 thr (16 waves). Wave wv owns hidden unit u=w*16+wv:
// lanes = (gate=lane>>4) x (kslice=lane&15), 32 W_hh weights/lane in VGPRs.
// Each wave IC-polls a disjoint 32-float share of h[t], deposits it into a
// swizzled LDS ring slot, bumps cnt[slot]; consumers spin on cnt==16 (no
// __syncthreads in the loop). Gate math is wave-uniform via readlane.
// Ring-slot counter reset at distance 2 is ordered by the data-dep chain.
// ---------------------------------------------------------------------------
#define DPP_ROR_ADD(v, ctrl) do { \
    int _t = __builtin_amdgcn_update_dpp(0, __float_as_int(v), (ctrl), 0xf, 0xf, false); \
    (v) += __int_as_float(_t); } while (0)

#define RL_F(x, l) __uint_as_float((uint32_t)__builtin_amdgcn_readlane((int)__float_as_uint(x), (l)))

__global__ __launch_bounds__(1024, 4) void scan_k(
    const float* __restrict__ Whh_f, const float* __restrict__ Whh_b,
    const float* __restrict__ c0, const float* __restrict__ g,
    float* __restrict__ hbuf, float* __restrict__ out)
{
  const int bx   = blockIdx.x;
  const int dir  = bx >> 5;
  const int w    = bx & 31;
  const int tid  = threadIdx.x;
  const int lane = tid & 63;
  const int wv   = tid >> 6;          // 0..15: owned hidden unit (local)
  const int u    = (w << 4) + wv;     // global hidden unit 0..511
  const int g4   = lane >> 4;         // gate 0..3 (i,f,g,o)
  const int ks   = lane & 15;         // k-slice: h[32ks .. 32ks+32)

  const float* __restrict__ Whh = dir ? Whh_b : Whh_f;

  __shared__ float hring[4][HH];      // h[t] ring, chunk-swizzled
  __shared__ int   cnt[4];            // per-slot deposit counters

  // Recurrent weights for row (g4*512 + u), k in [32ks, 32ks+32): 32 VGPRs.
  float wr[32];
  {
    const float* wp = &Whh[(size_t)(g4*HH + u)*HH + (ks<<5)];
    #pragma unroll
    for (int q = 0; q < 8; q++){
      vf4 t4 = *(const vf4*)&wp[q<<2];
      wr[4*q+0]=t4.x; wr[4*q+1]=t4.y; wr[4*q+2]=t4.z; wr[4*q+3]=t4.w;
    }
  }

  float cst = c0[dir*HH + u];         // wave-uniform cell state
  if (tid < 4) cnt[tid] = 0;

  float* __restrict__ hb = hbuf + (size_t)dir*(NSEQ+1)*HH;
  const float* __restrict__ gbp = g + (size_t)dir*NSEQ*FOURH;

  // g for step 0 (lanes ks==0 hold gate g4's value)
  float gc = 0.f;
  if (ks == 0) gc = gbp[(size_t)g4*HH + u];

  __syncthreads();                    // cnt zero + weights visible

  int  budget = 1 << 21;              // global fail-fast budget (never hangs)
  bool bail   = false;

  for (int t = 0; t < NSEQ; t++){
    const int slot = t & 3;

    // --- IC poll of this wave's 32-float share of h[t]; deposit to LDS ---
    if (lane < 8){
      const float* hp = &hb[(size_t)t*HH + (wv<<5) + (lane<<2)];
      vf4 v;
      for (;;){
        v = ld16_ic(hp);
        int ok = (__float_as_uint(v.x)!=POISON) & (__float_as_uint(v.y)!=POISON)
               & (__float_as_uint(v.z)!=POISON) & (__float_as_uint(v.w)!=POISON);
        if (__all(ok)) break;
        if (--budget < 0){ bail = true; break; }
      }
      // chunk c = 8*wv + lane; swizzle column by (wv&7) -> conflict-free b128
      const int c = (wv << 3) | lane;
      const int p = (c & ~7) | ((c & 7) ^ (wv & 7));
      *(vf4*)&hring[slot][p << 2] = v;
    }
    asm volatile("s_waitcnt lgkmcnt(0)" ::: "memory");  // deposits before count
    if (lane == 0) atomicAdd(&cnt[slot], 1);
    if (tid == 0) *(volatile int*)&cnt[(t + 2) & 3] = 0; // safe: dep-chain ordered

    // --- g prefetch for step t+1 (overlaps the spin below) ---
    float gn = 0.f;
    if (ks == 0){
      int tn = (t+1 < NSEQ) ? t+1 : NSEQ-1;
      gn = gbp[(size_t)tn*FOURH + g4*HH + u];
    }

    // --- wait for all 16 deposits (LDS spin, no barrier) ---
    {
      volatile int* cp = &cnt[slot];
      while (*cp != 16){ if (--budget < 0){ bail = true; break; } }
    }
    __threadfence_block();
    if (__any((int)bail)) break;

    // --- 32-long dot per lane from swizzled LDS (phys col = q ^ (ks&7)) ---
    const int   s7 = ks & 7;
    const float* hr = &hring[slot][0];
    float a0=0.f, a1=0.f, a2=0.f, a3=0.f;
    #pragma unroll
    for (int q = 0; q < 8; q++){
      vf4 h4 = *(const vf4*)&hr[(((ks << 3) | (q ^ s7))) << 2];
      a0 += wr[4*q+0]*h4.x; a1 += wr[4*q+1]*h4.y;
      a2 += wr[4*q+2]*h4.z; a3 += wr[4*q+3]*h4.w;
    }
    float acc = (a0 + a1) + (a2 + a3);

    // --- reduce across the 16 k-slices within each gate group ---
    DPP_ROR_ADD(acc, 0x121); DPP_ROR_ADD(acc, 0x122);
    DPP_ROR_ADD(acc, 0x124); DPP_ROR_ADD(acc, 0x128);

    // --- gather z per gate + gate math (wave-uniform) ---
    float zi = RL_F(acc,  0) + RL_F(gc,  0);
    float zf = RL_F(acc, 16) + RL_F(gc, 16);
    float zg = RL_F(acc, 32) + RL_F(gc, 32);
    float zo = RL_F(acc, 48) + RL_F(gc, 48);
    float si = 1.f/(1.f + __expf(-zi));
    float sf = 1.f/(1.f + __expf(-zf));
    float so = 1.f/(1.f + __expf(-zo));
    float e2g = __expf(2.f*zg);
    float tg  = (e2g - 1.f)/(e2g + 1.f);
    cst = sf*cst + si*tg;
    float e2c = __expf(2.f*cst);
    float tc  = (e2c - 1.f)/(e2c + 1.f);
    float hv  = so*tc;
    if (__float_as_uint(hv) == POISON) hv = __uint_as_float(POISON ^ 1u);

    // --- publish ---
    if (lane == 0){
      const int n = dir ? (t ^ 7) : t;              // undo per-sample reversal
      out[(size_t)n*(2*HH) + dir*HH + u] = hv;
      st_ic(&hb[(size_t)(t+1)*HH + u], hv);
      if (t == NSEQ-1){
        out[(size_t)NSEQ*2*HH + dir*HH + u] = hv;           // h_n
        out[(size_t)NSEQ*2*HH + 2*HH + dir*HH + u] = cst;   // c_n
      }
    }
    gc = gn;
  }
}

// ---------------------------------------------------------------------------
extern "C" void kernel_launch(void* const* d_in, const int* in_sizes, int n_in,
                              void* d_out, int out_size, void* d_ws, size_t ws_size,
                              hipStream_t stream)
{
  const float* x    = (const float*)d_in[0];
  const float* h0   = (const float*)d_in[1];
  const float* c0   = (const float*)d_in[2];
  const float* Wihf = (const float*)d_in[3];
  const float* Whhf = (const float*)d_in[4];
  const float* bf   = (const float*)d_in[5];
  const float* Wihb = (const float*)d_in[6];
  const float* Whhb = (const float*)d_in[7];
  const float* bb   = (const float*)d_in[8];
  float* out = (float*)d_out;
  float* ws  = (float*)d_ws;

  float* g    = ws;                 // [2][8192][2048] fp32
  float* hbuf = ws + G_ELEMS;       // [2][8193][512]  fp32

  {
    int total = (int)HB_ELEMS;
    int blocks = (total + 255) / 256;
    init_hbuf_k<<<blocks, 256, 0, stream>>>(hbuf, h0);
  }
  {
    dim3 grid(NSEQ/64, (2*FOURH)/64);   // (128, 64)
    gemm_ih_k<<<grid, 256, 0, stream>>>(x, Wihf, bf, Wihb, bb, g);
  }
  scan_k<<<64, 1024, 0, stream>>>(Whhf, Whhb, c0, g, hbuf, out);
}

// Round 4
// 28939.874 us; speedup vs baseline: 1.0889x; 1.0889x over previous
//
#include <hip/hip_runtime.h>
#include <stdint.h>

// Problem dims (fixed by the reference)
#define BSZ   1024
#define TT    8
#define DD    512
#define HH    512
#define NSEQ  (BSZ*TT)          // 8192 sequential steps per direction
#define FOURH (4*HH)            // 2048
#define POISON 0xAAAAAAAAu
#define G_ELEMS  ((size_t)2*NSEQ*FOURH)      // 33,554,432 floats (128 MB)
#define HB_ELEMS ((size_t)2*(NSEQ+1)*HH)     //  8,389,632 floats (32 MB)

typedef __attribute__((ext_vector_type(4))) float vf4;

// IC-coherent 2x16B load (bypasses L1+L2; single vmcnt wait for both).
__device__ __forceinline__ void ld2x16_ic(const float* p, vf4& a, vf4& b){
  asm volatile("global_load_dwordx4 %0, %2, off sc0 sc1\n\t"
               "global_load_dwordx4 %1, %2, off offset:16 sc0 sc1\n\t"
               "s_waitcnt vmcnt(0)"
               : "=v"(a), "=v"(b) : "v"(p) : "memory");
}
// IC-coherent 4B publish store.
__device__ __forceinline__ void st_ic(float* p, float v){
  asm volatile("global_store_dword %0, %1, off sc0 sc1"
               :: "v"(p), "v"(v) : "memory");
}

// ---------------------------------------------------------------------------
// Init: poison the h-pipeline buffer, seed slot 0 with h0 (LSB-flip if it
// happens to equal the poison bit pattern).
// ---------------------------------------------------------------------------
__global__ void init_hbuf_k(float* __restrict__ hbuf, const float* __restrict__ h0)
{
  size_t idx = (size_t)blockIdx.x*blockDim.x + threadIdx.x;
  if (idx >= HB_ELEMS) return;
  int j = (int)(idx % HH);
  size_t r = idx / HH;
  int t   = (int)(r % (NSEQ+1));
  int dir = (int)(r / (NSEQ+1));
  uint32_t v;
  if (t == 0){
    uint32_t u = __float_as_uint(h0[dir*HH + j]);
    if (u == POISON) u ^= 1u;
    v = u;
  } else {
    v = POISON;
  }
  ((uint32_t*)hbuf)[idx] = v;
}

// ---------------------------------------------------------------------------
// Input-side GEMM: g[dir][n][m] = x[row]·W_ih_dir[m] + b_dir[m]
//   dir 0: row = n ; dir 1: row = n^7  (per-sample time reversal, T=8)
// ---------------------------------------------------------------------------
__global__ __launch_bounds__(256) void gemm_ih_k(
    const float* __restrict__ x,
    const float* __restrict__ Wf, const float* __restrict__ bf,
    const float* __restrict__ Wb, const float* __restrict__ bb,
    float* __restrict__ g)
{
  const int bm = blockIdx.x;          // 128 row tiles
  const int bn = blockIdx.y;          // 64 col tiles over combined N=4096
  const int n0  = bm*64;
  const int m0g = bn*64;
  const int dir = m0g >> 11;          // /2048
  const int m0  = m0g & 2047;
  const float* __restrict__ W    = dir ? Wb : Wf;
  const float* __restrict__ bias = dir ? bb : bf;

  __shared__ float As[32][68];
  __shared__ float Bs[32][68];

  const int tid = threadIdx.x;
  const int tx = tid & 15, ty = tid >> 4;
  float acc[4][4] = {};

  const int lr = tid >> 2;            // 0..63
  const int lk = (tid & 3) * 8;       // 0,8,16,24
  int arow = n0 + lr; if (dir) arow ^= 7;
  const float* ap = &x[(size_t)arow*DD];
  const float* wp = &W[(size_t)(m0+lr)*DD];

  for (int k0 = 0; k0 < DD; k0 += 32){
    float4 a0 = *(const float4*)&ap[k0+lk];
    float4 a1 = *(const float4*)&ap[k0+lk+4];
    float4 w0 = *(const float4*)&wp[k0+lk];
    float4 w1 = *(const float4*)&wp[k0+lk+4];
    __syncthreads();
    As[lk+0][lr]=a0.x; As[lk+1][lr]=a0.y; As[lk+2][lr]=a0.z; As[lk+3][lr]=a0.w;
    As[lk+4][lr]=a1.x; As[lk+5][lr]=a1.y; As[lk+6][lr]=a1.z; As[lk+7][lr]=a1.w;
    Bs[lk+0][lr]=w0.x; Bs[lk+1][lr]=w0.y; Bs[lk+2][lr]=w0.z; Bs[lk+3][lr]=w0.w;
    Bs[lk+4][lr]=w1.x; Bs[lk+5][lr]=w1.y; Bs[lk+6][lr]=w1.z; Bs[lk+7][lr]=w1.w;
    __syncthreads();
    #pragma unroll
    for (int kk = 0; kk < 32; kk++){
      float4 av = *(const float4*)&As[kk][ty*4];
      float4 bv = *(const float4*)&Bs[kk][tx*4];
      acc[0][0]+=av.x*bv.x; acc[0][1]+=av.x*bv.y; acc[0][2]+=av.x*bv.z; acc[0][3]+=av.x*bv.w;
      acc[1][0]+=av.y*bv.x; acc[1][1]+=av.y*bv.y; acc[1][2]+=av.y*bv.z; acc[1][3]+=av.y*bv.w;
      acc[2][0]+=av.z*bv.x; acc[2][1]+=av.z*bv.y; acc[2][2]+=av.z*bv.z; acc[2][3]+=av.z*bv.w;
      acc[3][0]+=av.w*bv.x; acc[3][1]+=av.w*bv.y; acc[3][2]+=av.w*bv.z; acc[3][3]+=av.w*bv.w;
    }
  }

  const size_t gbase = (size_t)dir*NSEQ*FOURH;
  #pragma unroll
  for (int i = 0; i < 4; i++){
    const int n = n0 + ty*4 + i;
    #pragma unroll
    for (int j = 0; j < 4; j++){
      const int m = m0 + tx*4 + j;
      g[gbase + (size_t)n*FOURH + m] = acc[i][j] + bias[m];
    }
  }
}

// ---------------------------------------------------------------------------
// Sequential bidirectional scan — one barrier per step, no spins.
// 64 wgs (32/dir) x 1024 thr (16 waves). Wave wv owns hidden unit u=w*16+wv:
// lanes = (gate=lane>>4) x (kslice=lane&15), 32 W_hh weights/lane in VGPRs.
// Wave 0 IC-polls all 512 floats of h[t] and deposits into a double-buffered
// swizzled LDS tile; waves 1-15 PARK at __syncthreads (no LDS spins). After
// the barrier each wave computes its unit (DPP reduce + readlane + uniform
// gate math) and lane 0 publishes h[t+1][u] via a 4B IC store.
// Swizzle p = c ^ ((c>>3)&7): conflict-free for both the 2-chunk/lane deposit
// and the 8-chunk/lane compute reads (2-way max = free).
// ---------------------------------------------------------------------------
#define DPP_ROR_ADD(v, ctrl) do { \
    int _t = __builtin_amdgcn_update_dpp(0, __float_as_int(v), (ctrl), 0xf, 0xf, false); \
    (v) += __int_as_float(_t); } while (0)

#define RL_F(x, l) __uint_as_float((uint32_t)__builtin_amdgcn_readlane((int)__float_as_uint(x), (l)))

__global__ __launch_bounds__(1024, 4) void scan_k(
    const float* __restrict__ Whh_f, const float* __restrict__ Whh_b,
    const float* __restrict__ c0, const float* __restrict__ g,
    float* __restrict__ hbuf, float* __restrict__ out)
{
  const int bx   = blockIdx.x;
  const int dir  = bx >> 5;
  const int w    = bx & 31;
  const int tid  = threadIdx.x;
  const int lane = tid & 63;
  const int wv   = tid >> 6;          // 0..15: owned hidden unit (local)
  const int u    = (w << 4) + wv;     // global hidden unit 0..511
  const int g4   = lane >> 4;         // gate 0..3 (i,f,g,o)
  const int ks   = lane & 15;         // k-slice: h[32ks .. 32ks+32)

  const float* __restrict__ Whh = dir ? Whh_b : Whh_f;

  __shared__ vf4 hsh[2][128];         // h[t] tile, double-buffered, swizzled
  __shared__ int dead;

  // Recurrent weights for row (g4*512 + u), k in [32ks, 32ks+32): 32 VGPRs.
  float wr[32];
  {
    const float* wp = &Whh[(size_t)(g4*HH + u)*HH + (ks<<5)];
    #pragma unroll
    for (int q = 0; q < 8; q++){
      vf4 t4 = *(const vf4*)&wp[q<<2];
      wr[4*q+0]=t4.x; wr[4*q+1]=t4.y; wr[4*q+2]=t4.z; wr[4*q+3]=t4.w;
    }
  }

  float cst = c0[dir*HH + u];         // wave-uniform cell state
  if (tid == 0) dead = 0;

  float* __restrict__ hb = hbuf + (size_t)dir*(NSEQ+1)*HH;
  const float* __restrict__ gbp = g + (size_t)dir*NSEQ*FOURH;

  // g for step 0 (lanes ks==0 hold gate g4's value for unit u)
  float gc = 0.f;
  if (ks == 0) gc = gbp[(size_t)g4*HH + u];

  __syncthreads();

  int budget = 1 << 22;               // fail-fast; never hangs

  for (int t = 0; t < NSEQ; t++){
    vf4* hs = hsh[t & 1];

    // --- wave 0: poll h[t] (8 floats/lane) from IC; deposit swizzled ---
    if (wv == 0){
      const float* hp = &hb[(size_t)t*HH + (lane<<3)];
      vf4 a, b;
      for (;;){
        ld2x16_ic(hp, a, b);
        int ok = (__float_as_uint(a.x)!=POISON) & (__float_as_uint(a.y)!=POISON)
               & (__float_as_uint(a.z)!=POISON) & (__float_as_uint(a.w)!=POISON)
               & (__float_as_uint(b.x)!=POISON) & (__float_as_uint(b.y)!=POISON)
               & (__float_as_uint(b.z)!=POISON) & (__float_as_uint(b.w)!=POISON);
        if (__all(ok)) break;
        if (--budget < 0){ dead = 1; break; }
      }
      const int c0i = lane << 1, c1i = c0i + 1;
      hs[c0i ^ ((c0i >> 3) & 7)] = a;
      hs[c1i ^ ((c1i >> 3) & 7)] = b;
    }
    __syncthreads();                  // waves 1-15 park here during the poll
    if (dead) break;                  // uniform bail (LDS read after barrier)

    // --- g prefetch for step t+1: issued now, drained while parked at the
    //     next barrier (overlaps wave 0's poll) ---
    float gn = 0.f;
    if (ks == 0){
      int tn = (t+1 < NSEQ) ? t+1 : NSEQ-1;
      gn = gbp[(size_t)tn*FOURH + g4*HH + u];
    }

    // --- 32-long dot per lane from swizzled LDS ---
    const int s7 = ks & 7;
    float a0=0.f, a1=0.f, a2=0.f, a3=0.f;
    #pragma unroll
    for (int q = 0; q < 8; q++){
      vf4 h4 = hs[(ks << 3) | (q ^ s7)];
      a0 += wr[4*q+0]*h4.x; a1 += wr[4*q+1]*h4.y;
      a2 += wr[4*q+2]*h4.z; a3 += wr[4*q+3]*h4.w;
    }
    float acc = (a0 + a1) + (a2 + a3);

    // --- reduce across the 16 k-slices within each gate group ---
    DPP_ROR_ADD(acc, 0x121); DPP_ROR_ADD(acc, 0x122);
    DPP_ROR_ADD(acc, 0x124); DPP_ROR_ADD(acc, 0x128);

    // --- gather z per gate + gate math (wave-uniform) ---
    float zi = RL_F(acc,  0) + RL_F(gc,  0);
    float zf = RL_F(acc, 16) + RL_F(gc, 16);
    float zg = RL_F(acc, 32) + RL_F(gc, 32);
    float zo = RL_F(acc, 48) + RL_F(gc, 48);
    float si = 1.f/(1.f + __expf(-zi));
    float sf = 1.f/(1.f + __expf(-zf));
    float so = 1.f/(1.f + __expf(-zo));
    float e2g = __expf(2.f*zg);
    float tg  = (e2g - 1.f)/(e2g + 1.f);
    cst = sf*cst + si*tg;
    float e2c = __expf(2.f*cst);
    float tc  = (e2c - 1.f)/(e2c + 1.f);
    float hv  = so*tc;
    if (__float_as_uint(hv) == POISON) hv = __uint_as_float(POISON ^ 1u);

    // --- publish (prompt: first thing after hv) ---
    if (lane == 0){
      st_ic(&hb[(size_t)(t+1)*HH + u], hv);
      const int n = dir ? (t ^ 7) : t;              // undo per-sample reversal
      out[(size_t)n*(2*HH) + dir*HH + u] = hv;
      if (t == NSEQ-1){
        out[(size_t)NSEQ*2*HH + dir*HH + u] = hv;           // h_n
        out[(size_t)NSEQ*2*HH + 2*HH + dir*HH + u] = cst;   // c_n
      }
    }
    gc = gn;
    // No second barrier: double-buffered hsh makes wave 0's t+1 deposits safe
    // against stragglers still reading buffer t&1.
  }
}

// ---------------------------------------------------------------------------
extern "C" void kernel_launch(void* const* d_in, const int* in_sizes, int n_in,
                              void* d_out, int out_size, void* d_ws, size_t ws_size,
                              hipStream_t stream)
{
  const float* x    = (const float*)d_in[0];
  const float* h0   = (const float*)d_in[1];
  const float* c0   = (const float*)d_in[2];
  const float* Wihf = (const float*)d_in[3];
  const float* Whhf = (const float*)d_in[4];
  const float* bf   = (const float*)d_in[5];
  const float* Wihb = (const float*)d_in[6];
  const float* Whhb = (const float*)d_in[7];
  const float* bb   = (const float*)d_in[8];
  float* out = (float*)d_out;
  float* ws  = (float*)d_ws;

  float* g    = ws;                 // [2][8192][2048] fp32
  float* hbuf = ws + G_ELEMS;       // [2][8193][512]  fp32

  {
    int total = (int)HB_ELEMS;
    int blocks = (total + 255) / 256;
    init_hbuf_k<<<blocks, 256, 0, stream>>>(hbuf, h0);
  }
  {
    dim3 grid(NSEQ/64, (2*FOURH)/64);   // (128, 64)
    gemm_ih_k<<<grid, 256, 0, stream>>>(x, Wihf, bf, Wihb, bb, g);
  }
  scan_k<<<64, 1024, 0, stream>>>(Whhf, Whhb, c0, g, hbuf, out);
}

// Round 5
// 15542.340 us; speedup vs baseline: 2.0276x; 1.8620x over previous
//
#include <hip/hip_runtime.h>
#include <stdint.h>

// Problem dims (fixed by the reference)
#define BSZ   1024
#define TT    8
#define DD    512
#define HH    512
#define NSEQ  (BSZ*TT)          // 8192 sequential steps per direction
#define FOURH (4*HH)            // 2048
#define POISON 0xAAAAAAAAu
#define G_ELEMS  ((size_t)2*NSEQ*FOURH)      // 33,554,432 floats (128 MB)
#define HB_ELEMS ((size_t)2*(NSEQ+1)*HH)     //  8,389,632 floats (32 MB)

#define UPW 8                   // units per workgroup
#define SCAN_WGS (2*(HH/UPW))   // 128

typedef __attribute__((ext_vector_type(4))) float vf4;

// IC-coherent 2x16B load (bypasses L1+L2; no cache-invalidate side effects).
__device__ __forceinline__ void ld2x16_ic(const float* p, vf4& a, vf4& b){
  asm volatile("global_load_dwordx4 %0, %2, off sc0 sc1\n\t"
               "global_load_dwordx4 %1, %2, off offset:16 sc0 sc1\n\t"
               "s_waitcnt vmcnt(0)"
               : "=v"(a), "=v"(b) : "v"(p) : "memory");
}
// IC-coherent 4B publish store.
__device__ __forceinline__ void st_ic(float* p, float v){
  asm volatile("global_store_dword %0, %1, off sc0 sc1"
               :: "v"(p), "v"(v) : "memory");
}

// ---------------------------------------------------------------------------
// Init: poison the h-pipeline buffer, seed slot 0 with h0 (LSB-flip if it
// happens to equal the poison bit pattern).
// ---------------------------------------------------------------------------
__global__ void init_hbuf_k(float* __restrict__ hbuf, const float* __restrict__ h0)
{
  size_t idx = (size_t)blockIdx.x*blockDim.x + threadIdx.x;
  if (idx >= HB_ELEMS) return;
  int j = (int)(idx % HH);
  size_t r = idx / HH;
  int t   = (int)(r % (NSEQ+1));
  int dir = (int)(r / (NSEQ+1));
  uint32_t v;
  if (t == 0){
    uint32_t u = __float_as_uint(h0[dir*HH + j]);
    if (u == POISON) u ^= 1u;
    v = u;
  } else {
    v = POISON;
  }
  ((uint32_t*)hbuf)[idx] = v;
}

// ---------------------------------------------------------------------------
// Input-side GEMM: g[dir][n][m] = x[row]·W_ih_dir[m] + b_dir[m]
//   dir 0: row = n ; dir 1: row = n^7  (per-sample time reversal, T=8)
// ---------------------------------------------------------------------------
__global__ __launch_bounds__(256) void gemm_ih_k(
    const float* __restrict__ x,
    const float* __restrict__ Wf, const float* __restrict__ bf,
    const float* __restrict__ Wb, const float* __restrict__ bb,
    float* __restrict__ g)
{
  const int bm = blockIdx.x;          // 128 row tiles
  const int bn = blockIdx.y;          // 64 col tiles over combined N=4096
  const int n0  = bm*64;
  const int m0g = bn*64;
  const int dir = m0g >> 11;          // /2048
  const int m0  = m0g & 2047;
  const float* __restrict__ W    = dir ? Wb : Wf;
  const float* __restrict__ bias = dir ? bb : bf;

  __shared__ float As[32][68];
  __shared__ float Bs[32][68];

  const int tid = threadIdx.x;
  const int tx = tid & 15, ty = tid >> 4;
  float acc[4][4] = {};

  const int lr = tid >> 2;            // 0..63
  const int lk = (tid & 3) * 8;       // 0,8,16,24
  int arow = n0 + lr; if (dir) arow ^= 7;
  const float* ap = &x[(size_t)arow*DD];
  const float* wp = &W[(size_t)(m0+lr)*DD];

  for (int k0 = 0; k0 < DD; k0 += 32){
    float4 a0 = *(const float4*)&ap[k0+lk];
    float4 a1 = *(const float4*)&ap[k0+lk+4];
    float4 w0 = *(const float4*)&wp[k0+lk];
    float4 w1 = *(const float4*)&wp[k0+lk+4];
    __syncthreads();
    As[lk+0][lr]=a0.x; As[lk+1][lr]=a0.y; As[lk+2][lr]=a0.z; As[lk+3][lr]=a0.w;
    As[lk+4][lr]=a1.x; As[lk+5][lr]=a1.y; As[lk+6][lr]=a1.z; As[lk+7][lr]=a1.w;
    Bs[lk+0][lr]=w0.x; Bs[lk+1][lr]=w0.y; Bs[lk+2][lr]=w0.z; Bs[lk+3][lr]=w0.w;
    Bs[lk+4][lr]=w1.x; Bs[lk+5][lr]=w1.y; Bs[lk+6][lr]=w1.z; Bs[lk+7][lr]=w1.w;
    __syncthreads();
    #pragma unroll
    for (int kk = 0; kk < 32; kk++){
      float4 av = *(const float4*)&As[kk][ty*4];
      float4 bv = *(const float4*)&Bs[kk][tx*4];
      acc[0][0]+=av.x*bv.x; acc[0][1]+=av.x*bv.y; acc[0][2]+=av.x*bv.z; acc[0][3]+=av.x*bv.w;
      acc[1][0]+=av.y*bv.x; acc[1][1]+=av.y*bv.y; acc[1][2]+=av.y*bv.z; acc[1][3]+=av.y*bv.w;
      acc[2][0]+=av.z*bv.x; acc[2][1]+=av.z*bv.y; acc[2][2]+=av.z*bv.z; acc[2][3]+=av.z*bv.w;
      acc[3][0]+=av.w*bv.x; acc[3][1]+=av.w*bv.y; acc[3][2]+=av.w*bv.z; acc[3][3]+=av.w*bv.w;
    }
  }

  const size_t gbase = (size_t)dir*NSEQ*FOURH;
  #pragma unroll
  for (int i = 0; i < 4; i++){
    const int n = n0 + ty*4 + i;
    #pragma unroll
    for (int j = 0; j < 4; j++){
      const int m = m0 + tx*4 + j;
      g[gbase + (size_t)n*FOURH + m] = acc[i][j] + bias[m];
    }
  }
}

// ---------------------------------------------------------------------------
// Sequential bidirectional scan.
// 128 wgs (64/dir) x 512 thr (8 waves). Wave wv owns hidden unit u = w*8+wv.
// Lane layout: lane = k-slice, covering h[8*lane .. 8*lane+8); each lane
// accumulates ALL FOUR gates over its 8 h-floats (32 weights in VGPRs) —
// minimal LDS traffic (2 linear b128 reads/lane) and minimal FMA count.
// Per step: wave 0 IC-polls h[t] (poison-carried validity), deposits to LDS
// (split-chunk layout: chunk 2L -> hs[L], 2L+1 -> hs[64+L]; all accesses are
// 16B-linear => conflict-free); ONE barrier; every wave computes its unit
// (row_ror DPP reduce + readlane, wave-uniform gates); lane0 drops hv into
// zout[wv]; wave 0 micro-spins on the 8 zout slots then publishes all 8 as a
// single coalesced 32B sc0sc1 store (fixes R3/R4's partial-sector scatter).
// g loads and out stores are non-temporal so the 160MB streams don't evict
// hbuf from the Infinity Cache (R3/R4 FETCH excess = poll misses to HBM).
// ---------------------------------------------------------------------------
#define DPP_ROR_ADD(v, ctrl) do { \
    int _t = __builtin_amdgcn_update_dpp(0, __float_as_int(v), (ctrl), 0xf, 0xf, false); \
    (v) += __int_as_float(_t); } while (0)

#define RL_F(x, l) __uint_as_float((uint32_t)__builtin_amdgcn_readlane((int)__float_as_uint(x), (l)))

// full-64-lane sum via proven row_ror-16 reduce + 4 readlanes
#define RED64(z, acc) do { \
    DPP_ROR_ADD(acc, 0x121); DPP_ROR_ADD(acc, 0x122); \
    DPP_ROR_ADD(acc, 0x124); DPP_ROR_ADD(acc, 0x128); \
    z = (RL_F(acc,0) + RL_F(acc,16)) + (RL_F(acc,32) + RL_F(acc,48)); } while (0)

__global__ __launch_bounds__(512, 2) void scan_k(
    const float* __restrict__ Whh_f, const float* __restrict__ Whh_b,
    const float* __restrict__ c0, const float* __restrict__ g,
    float* __restrict__ hbuf, float* __restrict__ out)
{
  const int bx   = blockIdx.x;
  const int dir  = bx >> 6;
  const int w    = bx & 63;
  const int u0   = w << 3;            // first unit of this wg
  const int tid  = threadIdx.x;
  const int lane = tid & 63;
  const int wv   = tid >> 6;          // 0..7: owned hidden unit (local)
  const int u    = u0 + wv;           // global hidden unit 0..511

  const float* __restrict__ Whh = dir ? Whh_b : Whh_f;

  __shared__ vf4   hs[2][128];        // h[t], double-buffered, split-chunk
  __shared__ float zout[2][UPW];      // per-wave hv funnel (poison-carried)
  __shared__ float hnb[UPW], cnb[UPW];
  __shared__ int   dead;

  // Recurrent weights: 4 gate rows of unit u, k in [8*lane, 8*lane+8).
  float wr[4][8];
  #pragma unroll
  for (int gg = 0; gg < 4; gg++){
    const float* wp = &Whh[(size_t)(gg*HH + u)*HH + (lane<<3)];
    vf4 w0 = *(const vf4*)wp;
    vf4 w1 = *(const vf4*)(wp+4);
    wr[gg][0]=w0.x; wr[gg][1]=w0.y; wr[gg][2]=w0.z; wr[gg][3]=w0.w;
    wr[gg][4]=w1.x; wr[gg][5]=w1.y; wr[gg][6]=w1.z; wr[gg][7]=w1.w;
  }

  float cst = c0[dir*HH + u];         // wave-uniform cell state

  float* __restrict__ hb = hbuf + (size_t)dir*(NSEQ+1)*HH;
  const float* __restrict__ gbp = g + (size_t)dir*NSEQ*FOURH;

  // g for step 0: lane gg<4 holds gate gg's value for unit u (nt load).
  float gc = 0.f;
  if (lane < 4) gc = __builtin_nontemporal_load(&gbp[(size_t)lane*HH + u]);

  if (tid < 2*UPW) zout[tid>>3][tid&7] = __uint_as_float(POISON);
  if (tid == 0) dead = 0;
  __syncthreads();

  int budget = 1 << 22;               // fail-fast; never hangs

  for (int t = 0; t < NSEQ; t++){
    vf4* hsb = hs[t & 1];

    // --- wave 0: IC-poll h[t] (8 floats/lane); deposit split-chunk ---
    if (wv == 0){
      const float* hp = &hb[(size_t)t*HH + (lane<<3)];
      vf4 a, b;
      for (;;){
        ld2x16_ic(hp, a, b);
        int ok = (__float_as_uint(a.x)!=POISON) & (__float_as_uint(a.y)!=POISON)
               & (__float_as_uint(a.z)!=POISON) & (__float_as_uint(a.w)!=POISON)
               & (__float_as_uint(b.x)!=POISON) & (__float_as_uint(b.y)!=POISON)
               & (__float_as_uint(b.z)!=POISON) & (__float_as_uint(b.w)!=POISON);
        if (__all(ok)) break;
        if (--budget < 0){ if (lane == 0) dead = 1; break; }
      }
      hsb[lane]      = a;             // chunk 2L   (16B-linear)
      hsb[64 + lane] = b;             // chunk 2L+1 (16B-linear)
    }
    __syncthreads();                  // waves 1-7 park here during the poll
    if (*(volatile int*)&dead) break; // uniform bail

    // --- g prefetch for step t+1 (nt; drains while parked next step) ---
    float gn = 0.f;
    if (lane < 4){
      int tn = (t+1 < NSEQ) ? t+1 : t;
      gn = __builtin_nontemporal_load(&gbp[(size_t)tn*FOURH + lane*HH + u]);
    }

    // --- this lane's 8 h-floats (2 linear b128 reads, conflict-free) ---
    vf4 hA = hsb[lane];
    vf4 hB = hsb[64 + lane];

    // --- 4 gates x 8 MACs ---
    float ai=0.f, af=0.f, ag=0.f, ao=0.f;
    ai += wr[0][0]*hA.x; ai += wr[0][1]*hA.y; ai += wr[0][2]*hA.z; ai += wr[0][3]*hA.w;
    ai += wr[0][4]*hB.x; ai += wr[0][5]*hB.y; ai += wr[0][6]*hB.z; ai += wr[0][7]*hB.w;
    af += wr[1][0]*hA.x; af += wr[1][1]*hA.y; af += wr[1][2]*hA.z; af += wr[1][3]*hA.w;
    af += wr[1][4]*hB.x; af += wr[1][5]*hB.y; af += wr[1][6]*hB.z; af += wr[1][7]*hB.w;
    ag += wr[2][0]*hA.x; ag += wr[2][1]*hA.y; ag += wr[2][2]*hA.z; ag += wr[2][3]*hA.w;
    ag += wr[2][4]*hB.x; ag += wr[2][5]*hB.y; ag += wr[2][6]*hB.z; ag += wr[2][7]*hB.w;
    ao += wr[3][0]*hA.x; ao += wr[3][1]*hA.y; ao += wr[3][2]*hA.z; ao += wr[3][3]*hA.w;
    ao += wr[3][4]*hB.x; ao += wr[3][5]*hB.y; ao += wr[3][6]*hB.z; ao += wr[3][7]*hB.w;

    // --- full-wave reductions (proven row_ror + readlane) ---
    float zi, zf, zg, zo;
    RED64(zi, ai); RED64(zf, af); RED64(zg, ag); RED64(zo, ao);

    // --- gate math (wave-uniform) ---
    zi += RL_F(gc, 0); zf += RL_F(gc, 1); zg += RL_F(gc, 2); zo += RL_F(gc, 3);
    float si = 1.f/(1.f + __expf(-zi));
    float sf = 1.f/(1.f + __expf(-zf));
    float so = 1.f/(1.f + __expf(-zo));
    float e2g = __expf(2.f*zg);
    float tg  = (e2g - 1.f)/(e2g + 1.f);
    cst = sf*cst + si*tg;
    float e2c = __expf(2.f*cst);
    float tc  = (e2c - 1.f)/(e2c + 1.f);
    float hv  = so*tc;
    if (__float_as_uint(hv) == POISON) hv = __uint_as_float(POISON ^ 1u);

    // --- funnel hv to wave 0 via LDS (poison-carried, no barrier) ---
    if (lane == 0){
      zout[t & 1][wv] = hv;
      if (t == NSEQ-1){ hnb[wv] = hv; cnb[wv] = cst; }
    }
    if (wv == 0){
      float v = hv;                   // slot 0 is our own
      if (lane < UPW){
        volatile float* zp = &zout[t & 1][lane];
        if (lane != 0){
          for (;;){
            v = *zp;
            if (__float_as_uint(v) != POISON) break;
            if (--budget < 0){ dead = 1; break; }
          }
        }
        // coalesced 32B publish + nt out-store + re-poison for step t+2
        st_ic(&hb[(size_t)(t+1)*HH + u0 + lane], v);
        const int n = dir ? (t ^ 7) : t;
        __builtin_nontemporal_store(v, &out[(size_t)n*(2*HH) + dir*HH + u0 + lane]);
        *zp = __uint_as_float(POISON);
      }
    }
    gc = gn;
    // No second barrier: hs double-buffer + zout poison re-arm keep WAR safe.
  }

  // --- h_n / c_n tail ---
  __syncthreads();
  if (tid < UPW){
    out[(size_t)NSEQ*2*HH + dir*HH + u0 + tid]        = hnb[tid];
    out[(size_t)NSEQ*2*HH + 2*HH + dir*HH + u0 + tid] = cnb[tid];
  }
}

// ---------------------------------------------------------------------------
extern "C" void kernel_launch(void* const* d_in, const int* in_sizes, int n_in,
                              void* d_out, int out_size, void* d_ws, size_t ws_size,
                              hipStream_t stream)
{
  const float* x    = (const float*)d_in[0];
  const float* h0   = (const float*)d_in[1];
  const float* c0   = (const float*)d_in[2];
  const float* Wihf = (const float*)d_in[3];
  const float* Whhf = (const float*)d_in[4];
  const float* bf   = (const float*)d_in[5];
  const float* Wihb = (const float*)d_in[6];
  const float* Whhb = (const float*)d_in[7];
  const float* bb   = (const float*)d_in[8];
  float* out = (float*)d_out;
  float* ws  = (float*)d_ws;

  float* g    = ws;                 // [2][8192][2048] fp32
  float* hbuf = ws + G_ELEMS;       // [2][8193][512]  fp32

  {
    int total = (int)HB_ELEMS;
    int blocks = (total + 255) / 256;
    init_hbuf_k<<<blocks, 256, 0, stream>>>(hbuf, h0);
  }
  {
    dim3 grid(NSEQ/64, (2*FOURH)/64);   // (128, 64)
    gemm_ih_k<<<grid, 256, 0, stream>>>(x, Wihf, bf, Wihb, bb, g);
  }
  scan_k<<<SCAN_WGS, 512, 0, stream>>>(Whhf, Whhb, c0, g, hbuf, out);
}

// Round 6
// 14425.365 us; speedup vs baseline: 2.1846x; 1.0774x over previous
//
#include <hip/hip_runtime.h>
#include <stdint.h>

// Problem dims (fixed by the reference)
#define BSZ   1024
#define TT    8
#define DD    512
#define HH    512
#define NSEQ  (BSZ*TT)          // 8192 sequential steps per direction
#define FOURH (4*HH)            // 2048
#define POISON 0xAAAAAAAAu
#define G_ELEMS  ((size_t)2*NSEQ*FOURH)      // 33,554,432 floats (128 MB)
#define HB_ELEMS ((size_t)2*(NSEQ+1)*HH)     //  8,389,632 floats (32 MB)

#define UPW 16                  // units per workgroup (2 per wave, 8 waves)

typedef __attribute__((ext_vector_type(4))) float vf4;

// L2-scope 2x16B poll load (sc0: bypass L1 only; hits XCD-coherent L2).
__device__ __forceinline__ void ld2x16_l2(const float* p, vf4& a, vf4& b){
  asm volatile("global_load_dwordx4 %0, %2, off sc0\n\t"
               "global_load_dwordx4 %1, %2, off offset:16 sc0\n\t"
               "s_waitcnt vmcnt(0)"
               : "=v"(a), "=v"(b) : "v"(p) : "memory");
}
// IC-scope 2x16B poll load (sc0 sc1: bypass L1+L2) — escalation fallback.
__device__ __forceinline__ void ld2x16_ic(const float* p, vf4& a, vf4& b){
  asm volatile("global_load_dwordx4 %0, %2, off sc0 sc1\n\t"
               "global_load_dwordx4 %1, %2, off offset:16 sc0 sc1\n\t"
               "s_waitcnt vmcnt(0)"
               : "=v"(a), "=v"(b) : "v"(p) : "memory");
}
// L2-scope publish store (updates XCD L2 — fast local-XCD visibility).
__device__ __forceinline__ void st_l2(float* p, float v){
  asm volatile("global_store_dword %0, %1, off sc0"
               :: "v"(p), "v"(v) : "memory");
}
// IC-scope insurance store (same value; guarantees cross-XCD visibility).
__device__ __forceinline__ void st_ic(float* p, float v){
  asm volatile("global_store_dword %0, %1, off sc0 sc1"
               :: "v"(p), "v"(v) : "memory");
}

// ---------------------------------------------------------------------------
// Init: poison the h-pipeline buffer, seed slot 0 with h0 (LSB-flip if it
// happens to equal the poison bit pattern).
// ---------------------------------------------------------------------------
__global__ void init_hbuf_k(float* __restrict__ hbuf, const float* __restrict__ h0)
{
  size_t idx = (size_t)blockIdx.x*blockDim.x + threadIdx.x;
  if (idx >= HB_ELEMS) return;
  int j = (int)(idx % HH);
  size_t r = idx / HH;
  int t   = (int)(r % (NSEQ+1));
  int dir = (int)(r / (NSEQ+1));
  uint32_t v;
  if (t == 0){
    uint32_t u = __float_as_uint(h0[dir*HH + j]);
    if (u == POISON) u ^= 1u;
    v = u;
  } else {
    v = POISON;
  }
  ((uint32_t*)hbuf)[idx] = v;
}

// ---------------------------------------------------------------------------
// Input-side GEMM: g[dir][n][m] = x[row]·W_ih_dir[m] + b_dir[m]
//   dir 0: row = n ; dir 1: row = n^7  (per-sample time reversal, T=8)
// ---------------------------------------------------------------------------
__global__ __launch_bounds__(256) void gemm_ih_k(
    const float* __restrict__ x,
    const float* __restrict__ Wf, const float* __restrict__ bf,
    const float* __restrict__ Wb, const float* __restrict__ bb,
    float* __restrict__ g)
{
  const int bm = blockIdx.x;          // 128 row tiles
  const int bn = blockIdx.y;          // 64 col tiles over combined N=4096
  const int n0  = bm*64;
  const int m0g = bn*64;
  const int dir = m0g >> 11;          // /2048
  const int m0  = m0g & 2047;
  const float* __restrict__ W    = dir ? Wb : Wf;
  const float* __restrict__ bias = dir ? bb : bf;

  __shared__ float As[32][68];
  __shared__ float Bs[32][68];

  const int tid = threadIdx.x;
  const int tx = tid & 15, ty = tid >> 4;
  float acc[4][4] = {};

  const int lr = tid >> 2;            // 0..63
  const int lk = (tid & 3) * 8;       // 0,8,16,24
  int arow = n0 + lr; if (dir) arow ^= 7;
  const float* ap = &x[(size_t)arow*DD];
  const float* wp = &W[(size_t)(m0+lr)*DD];

  for (int k0 = 0; k0 < DD; k0 += 32){
    float4 a0 = *(const float4*)&ap[k0+lk];
    float4 a1 = *(const float4*)&ap[k0+lk+4];
    float4 w0 = *(const float4*)&wp[k0+lk];
    float4 w1 = *(const float4*)&wp[k0+lk+4];
    __syncthreads();
    As[lk+0][lr]=a0.x; As[lk+1][lr]=a0.y; As[lk+2][lr]=a0.z; As[lk+3][lr]=a0.w;
    As[lk+4][lr]=a1.x; As[lk+5][lr]=a1.y; As[lk+6][lr]=a1.z; As[lk+7][lr]=a1.w;
    Bs[lk+0][lr]=w0.x; Bs[lk+1][lr]=w0.y; Bs[lk+2][lr]=w0.z; Bs[lk+3][lr]=w0.w;
    Bs[lk+4][lr]=w1.x; Bs[lk+5][lr]=w1.y; Bs[lk+6][lr]=w1.z; Bs[lk+7][lr]=w1.w;
    __syncthreads();
    #pragma unroll
    for (int kk = 0; kk < 32; kk++){
      float4 av = *(const float4*)&As[kk][ty*4];
      float4 bv = *(const float4*)&Bs[kk][tx*4];
      acc[0][0]+=av.x*bv.x; acc[0][1]+=av.x*bv.y; acc[0][2]+=av.x*bv.z; acc[0][3]+=av.x*bv.w;
      acc[1][0]+=av.y*bv.x; acc[1][1]+=av.y*bv.y; acc[1][2]+=av.y*bv.z; acc[1][3]+=av.y*bv.w;
      acc[2][0]+=av.z*bv.x; acc[2][1]+=av.z*bv.y; acc[2][2]+=av.z*bv.z; acc[2][3]+=av.z*bv.w;
      acc[3][0]+=av.w*bv.x; acc[3][1]+=av.w*bv.y; acc[3][2]+=av.w*bv.z; acc[3][3]+=av.w*bv.w;
    }
  }

  const size_t gbase = (size_t)dir*NSEQ*FOURH;
  #pragma unroll
  for (int i = 0; i < 4; i++){
    const int n = n0 + ty*4 + i;
    #pragma unroll
    for (int j = 0; j < 4; j++){
      const int m = m0 + tx*4 + j;
      g[gbase + (size_t)n*FOURH + m] = acc[i][j] + bias[m];
    }
  }
}

// ---------------------------------------------------------------------------
// Sequential bidirectional scan — XCD-local L2 sync.
// Grid 256 x 512thr; only bx%8<2 live (heuristic: blockIdx%8 == XCD id).
//   dir = bx%8, w = bx>>3 (0..31): 32 wgs/dir, expected all on ONE XCD.
// Wave wv owns units u0+2wv, u0+2wv+1 (lane = su*32 + ks; ks covers
// h[16ks..16ks+16), 4 gates x 16 MACs, 64 weights in VGPRs).
// Sync: producers st_l2 (XCD L2) then st_ic (IC insurance, same value);
// consumers poll sc0-first, sticky-escalate to sc0+sc1 after 64 misses.
// Value-carried validity (poison) throughout; fail-fast budget; one barrier
// per step; zout funnel + single coalesced 64B publish per wg.
// ---------------------------------------------------------------------------
#define DPP_ROR_ADD(v, ctrl) do { \
    int _t = __builtin_amdgcn_update_dpp(0, __float_as_int(v), (ctrl), 0xf, 0xf, false); \
    (v) += __int_as_float(_t); } while (0)

// sum over each 32-lane half; every lane ends with its half's total
#define RED32(acc) do { \
    DPP_ROR_ADD(acc, 0x121); DPP_ROR_ADD(acc, 0x122); \
    DPP_ROR_ADD(acc, 0x124); DPP_ROR_ADD(acc, 0x128); \
    acc += __int_as_float(__builtin_amdgcn_ds_swizzle(__float_as_int(acc), 0x401F)); \
  } while (0)

__global__ __launch_bounds__(512, 2) void scan_k(
    const float* __restrict__ Whh_f, const float* __restrict__ Whh_b,
    const float* __restrict__ c0, const float* __restrict__ g,
    float* __restrict__ hbuf, float* __restrict__ out)
{
  const int bx = blockIdx.x;
  const int xcd = bx & 7;
  if (xcd >= 2) return;               // only 64 live wgs (32 per XCD/dir)
  const int dir = xcd;
  const int w   = bx >> 3;            // 0..31
  const int u0  = w << 4;             // first of this wg's 16 units
  const int tid  = threadIdx.x;
  const int lane = tid & 63;
  const int wv   = tid >> 6;          // 0..7
  const int su   = lane >> 5;         // sub-unit 0/1
  const int ks   = lane & 31;         // k-slice: h[16ks .. 16ks+16)
  const int u    = u0 + (wv << 1) + su;

  const float* __restrict__ Whh = dir ? Whh_b : Whh_f;

  __shared__ vf4   hq[2][128];        // h[t] as hq[buf][j*32+ks], dbl-buffered
  __shared__ float zout[2][UPW];      // per-unit hv funnel (poison-carried)
  __shared__ int   dead;

  // Recurrent weights: 4 gate rows of unit u, k in [16ks, 16ks+16).
  float wr[4][16];
  #pragma unroll
  for (int gg = 0; gg < 4; gg++){
    const float* wp = &Whh[(size_t)(gg*HH + u)*HH + (ks<<4)];
    #pragma unroll
    for (int q = 0; q < 4; q++){
      vf4 t4 = *(const vf4*)&wp[q<<2];
      wr[gg][4*q+0]=t4.x; wr[gg][4*q+1]=t4.y; wr[gg][4*q+2]=t4.z; wr[gg][4*q+3]=t4.w;
    }
  }

  float cst = c0[dir*HH + u];         // per-lane (unit-uniform) cell state

  float* __restrict__ hb = hbuf + (size_t)dir*(NSEQ+1)*HH;
  const float* __restrict__ gbp = g + (size_t)dir*NSEQ*FOURH;

  // g for step 0: every lane loads its unit's 4 gate values (broadcast-coalesced)
  float gci, gcf, gcg, gco;
  gci = __builtin_nontemporal_load(&gbp[0*HH + u]);
  gcf = __builtin_nontemporal_load(&gbp[1*HH + u]);
  gcg = __builtin_nontemporal_load(&gbp[2*HH + u]);
  gco = __builtin_nontemporal_load(&gbp[3*HH + u]);

  if (tid < 2*UPW) ((uint32_t*)zout)[tid] = POISON;
  if (tid == 0) dead = 0;
  __syncthreads();

  int  budget = 1 << 22;              // fail-fast; never hangs
  bool esc = false;                   // sticky escalation to IC-scope polls

  for (int t = 0; t < NSEQ; t++){
    const int buf = t & 1;
    vf4* hsb = &hq[buf][0];

    // --- wave 0: poll h[t] (8 floats/lane); deposit j-major ---
    if (wv == 0){
      const float* hp = &hb[(size_t)t*HH + (lane<<3)];
      vf4 a, b;
      int tries = 0;
      for (;;){
        if (!esc) ld2x16_l2(hp, a, b);
        else      ld2x16_ic(hp, a, b);
        int ok = (__float_as_uint(a.x)!=POISON) & (__float_as_uint(a.y)!=POISON)
               & (__float_as_uint(a.z)!=POISON) & (__float_as_uint(a.w)!=POISON)
               & (__float_as_uint(b.x)!=POISON) & (__float_as_uint(b.y)!=POISON)
               & (__float_as_uint(b.z)!=POISON) & (__float_as_uint(b.w)!=POISON);
        if (__all(ok)) break;
        if (++tries > 64) esc = true;           // mapping fallback (sticky)
        if (--budget < 0){ if (lane == 0) dead = 1; break; }
      }
      // lane L holds h[8L..8L+8). j-major layout: hq[j][r], r=L>>1.
      //   L even: a->j0, b->j1 ; L odd: a->j2, b->j3   (16B-linear per half)
      const int r = lane >> 1;
      const int jbase = (lane & 1) << 1;        // 0 or 2
      hsb[jbase*32 + r]       = a;
      hsb[(jbase+1)*32 + r]   = b;
    }
    __syncthreads();                  // waves 1-7 park here during the poll
    if (*(volatile int*)&dead) break;

    // --- g prefetch for step t+1 (nt; drains during next park) ---
    float gni, gnf, gng, gno;
    {
      const size_t gb = (size_t)((t+1 < NSEQ) ? t+1 : t)*FOURH;
      gni = __builtin_nontemporal_load(&gbp[gb + 0*HH + u]);
      gnf = __builtin_nontemporal_load(&gbp[gb + 1*HH + u]);
      gng = __builtin_nontemporal_load(&gbp[gb + 2*HH + u]);
      gno = __builtin_nontemporal_load(&gbp[gb + 3*HH + u]);
    }

    // --- dot: 4 gates x 16 MACs from j-major LDS (lane-linear reads) ---
    float ai=0.f, af=0.f, ag=0.f, ao=0.f;
    #pragma unroll
    for (int j = 0; j < 4; j++){
      vf4 h4 = hsb[j*32 + ks];        // su=1 lanes broadcast-read su=0 addrs
      ai += wr[0][4*j+0]*h4.x; ai += wr[0][4*j+1]*h4.y;
      ai += wr[0][4*j+2]*h4.z; ai += wr[0][4*j+3]*h4.w;
      af += wr[1][4*j+0]*h4.x; af += wr[1][4*j+1]*h4.y;
      af += wr[1][4*j+2]*h4.z; af += wr[1][4*j+3]*h4.w;
      ag += wr[2][4*j+0]*h4.x; ag += wr[2][4*j+1]*h4.y;
      ag += wr[2][4*j+2]*h4.z; ag += wr[2][4*j+3]*h4.w;
      ao += wr[3][4*j+0]*h4.x; ao += wr[3][4*j+1]*h4.y;
      ao += wr[3][4*j+2]*h4.z; ao += wr[3][4*j+3]*h4.w;
    }

    // --- reduce each gate over the 32-lane half (all lanes get the sum) ---
    RED32(ai); RED32(af); RED32(ag); RED32(ao);

    // --- gate math (redundant across the 32 lanes of this unit) ---
    float zi = ai + gci, zf = af + gcf, zg = ag + gcg, zo = ao + gco;
    float si = 1.f/(1.f + __expf(-zi));
    float sf = 1.f/(1.f + __expf(-zf));
    float so = 1.f/(1.f + __expf(-zo));
    float e2g = __expf(2.f*zg);
    float tg  = (e2g - 1.f)/(e2g + 1.f);
    cst = sf*cst + si*tg;
    float e2c = __expf(2.f*cst);
    float tc  = (e2c - 1.f)/(e2c + 1.f);
    float hv  = so*tc;
    if (__float_as_uint(hv) == POISON) hv = __uint_as_float(POISON ^ 1u);

    // --- funnel to wave 0 (poison-carried LDS slots), then publish ---
    if (ks == 0){
      zout[buf][(wv << 1) + su] = hv;
      if (t == NSEQ-1){
        out[(size_t)NSEQ*2*HH + dir*HH + u]        = hv;    // h_n
        out[(size_t)NSEQ*2*HH + 2*HH + dir*HH + u] = cst;   // c_n
      }
    }
    if (wv == 0 && lane < UPW){
      volatile float* zp = &zout[buf][lane];
      float v;
      for (;;){
        v = *zp;
        if (__float_as_uint(v) != POISON) break;
        if (--budget < 0){ dead = 1; break; }
      }
      float* hp1 = &hb[(size_t)(t+1)*HH + u0 + lane];
      st_l2(hp1, v);                  // fast: XCD-L2 visibility
      st_ic(hp1, v);                  // insurance: IC visibility (same value)
      const int n = dir ? (t ^ 7) : t;
      __builtin_nontemporal_store(v, &out[(size_t)n*(2*HH) + dir*HH + u0 + lane]);
      *zp = __uint_as_float(POISON);  // re-arm for t+2 (ordered by dep chain)
    }
    gci = gni; gcf = gnf; gcg = gng; gco = gno;
    // No second barrier: hq double-buffer + zout re-arm ordering keep WAR safe.
  }
}

// ---------------------------------------------------------------------------
extern "C" void kernel_launch(void* const* d_in, const int* in_sizes, int n_in,
                              void* d_out, int out_size, void* d_ws, size_t ws_size,
                              hipStream_t stream)
{
  const float* x    = (const float*)d_in[0];
  const float* h0   = (const float*)d_in[1];
  const float* c0   = (const float*)d_in[2];
  const float* Wihf = (const float*)d_in[3];
  const float* Whhf = (const float*)d_in[4];
  const float* bf   = (const float*)d_in[5];
  const float* Wihb = (const float*)d_in[6];
  const float* Whhb = (const float*)d_in[7];
  const float* bb   = (const float*)d_in[8];
  float* out = (float*)d_out;
  float* ws  = (float*)d_ws;

  float* g    = ws;                 // [2][8192][2048] fp32
  float* hbuf = ws + G_ELEMS;       // [2][8193][512]  fp32

  {
    int total = (int)HB_ELEMS;
    int blocks = (total + 255) / 256;
    init_hbuf_k<<<blocks, 256, 0, stream>>>(hbuf, h0);
  }
  {
    dim3 grid(NSEQ/64, (2*FOURH)/64);   // (128, 64)
    gemm_ih_k<<<grid, 256, 0, stream>>>(x, Wihf, bf, Wihb, bb, g);
  }
  scan_k<<<256, 512, 0, stream>>>(Whhf, Whhb, c0, g, hbuf, out);
}